// Round 4
// baseline (10251.189 us; speedup 1.0000x reference)
//
#include <hip/hip_runtime.h>
#include <hip/hip_bf16.h>
#include <stdint.h>
#include <stddef.h>

// Problem constants
#define B_   4096
#define H_   1024
#define L_   256
#define C_   128
#define T_   64
#define H3_  3072

typedef unsigned short u16;
typedef __attribute__((ext_vector_type(8))) short bf16x8;   // 8 bf16 = 4 VGPRs
typedef __attribute__((ext_vector_type(4))) float f32x4;

typedef const void __attribute__((address_space(1)))* as1_cvp;
typedef void __attribute__((address_space(3)))* as3_vp;

__device__ __forceinline__ void gl2lds16(const void* g, void* l) {
  __builtin_amdgcn_global_load_lds((as1_cvp)g, (as3_vp)l, 16, 0, 0);
}

__device__ __forceinline__ float bf2f(u16 u) {
  union { float f; unsigned int i; } x; x.i = ((unsigned int)u) << 16; return x.f;
}
__device__ __forceinline__ u16 f2bf(float f) {
  union { float f; unsigned int i; } x; x.f = f;
  unsigned int r = x.i + 0x7fffu + ((x.i >> 16) & 1u);  // RNE
  return (u16)(r >> 16);
}
__device__ __forceinline__ float sigm(float x) { return 1.f / (1.f + __expf(-x)); }
__device__ __forceinline__ float tanh_fast(float x) {
  float e = __expf(2.f * x); return 1.f - 2.f / (e + 1.f);
}

// ---------------------------------------------------------------------------
// 128x128-tile bf16 GEMM body (m97 structure): C[M,N] = A[M,K] @ W[N,K]^T +bias
// OUT_MODE: 0 = fp32 C0, 1 = bf16 C0, 2 = bf16 to C0 AND C1.
// ---------------------------------------------------------------------------
template<int OUT_MODE>
__device__ __forceinline__ void gemm_tile_body(
    u16* As, u16* Ws,
    const u16* __restrict__ A, int lda,
    const u16* __restrict__ W, int ldw,
    const float* __restrict__ bias,
    void* __restrict__ C0p, void* __restrict__ C1p, int ldc, int K,
    int m0, int n0)
{
  const int tid  = threadIdx.x;
  const int wave = tid >> 6, lane = tid & 63;
  const int wm = (wave >> 1) * 64, wn = (wave & 1) * 64;
  const int lrow = lane & 15, lq = lane >> 4;
  const int arow = wave * 8 + (lane >> 3);
  const int acol = (lane & 7) * 8;

  f32x4 acc[4][4] = {};

  const u16* Ag = A + (size_t)m0 * lda;
  const u16* Wg = W + (size_t)n0 * ldw;

  for (int k0 = 0; k0 < K; k0 += 64) {
    __syncthreads();
    #pragma unroll
    for (int rd = 0; rd < 4; rd++) {
      gl2lds16(Ag + (size_t)(rd * 32 + arow) * lda + (k0 + acol), As + rd * 2048 + wave * 512);
      gl2lds16(Wg + (size_t)(rd * 32 + arow) * ldw + (k0 + acol), Ws + rd * 2048 + wave * 512);
    }
    __syncthreads();
    #pragma unroll
    for (int kk = 0; kk < 64; kk += 32) {
      bf16x8 af[4], bw[4];
      #pragma unroll
      for (int i = 0; i < 4; i++)
        af[i] = *(const bf16x8*)&As[(wm + i * 16 + lrow) * 64 + kk + lq * 8];
      #pragma unroll
      for (int j = 0; j < 4; j++)
        bw[j] = *(const bf16x8*)&Ws[(wn + j * 16 + lrow) * 64 + kk + lq * 8];
      #pragma unroll
      for (int i = 0; i < 4; i++)
        #pragma unroll
        for (int j = 0; j < 4; j++)
          acc[i][j] = __builtin_amdgcn_mfma_f32_16x16x32_bf16(af[i], bw[j], acc[i][j], 0, 0, 0);
    }
  }

  #pragma unroll
  for (int j = 0; j < 4; j++) {
    const int col = n0 + wn + j * 16 + lrow;
    const float bv = bias ? bias[col] : 0.f;
    #pragma unroll
    for (int i = 0; i < 4; i++) {
      #pragma unroll
      for (int r = 0; r < 4; r++) {
        const int row = m0 + wm + i * 16 + lq * 4 + r;
        float v = acc[i][j][r] + bv;
        if (OUT_MODE == 0) {
          ((float*)C0p)[(size_t)row * ldc + col] = v;
        } else if (OUT_MODE == 1) {
          ((u16*)C0p)[(size_t)row * ldc + col] = f2bf(v);
        } else {
          u16 hv = f2bf(v);
          ((u16*)C0p)[(size_t)row * ldc + col] = hv;
          ((u16*)C1p)[(size_t)row * ldc + col] = hv;
        }
      }
    }
  }
}

template<int OUT_MODE>
__global__ __launch_bounds__(256) void gemm_bt(
    const u16* __restrict__ A, int lda,
    const u16* __restrict__ W, int ldw,
    const float* __restrict__ bias,
    void* __restrict__ C0p, void* __restrict__ C1p, int ldc, int K)
{
  __shared__ __align__(16) u16 As[128 * 64];
  __shared__ __align__(16) u16 Ws[128 * 64];
  gemm_tile_body<OUT_MODE>(As, Ws, A, lda, W, ldw, bias, C0p, C1p, ldc, K,
                           blockIdx.y * 128, blockIdx.x * 128);
}

// ---------------------------------------------------------------------------
// Shared K-loop for gate-fused GEMMs: A[128b] x W[3 gates x 64 j], K=1024.
// Accumulates gates g<3 into acc (or n-gate into accN when PH2).
// ---------------------------------------------------------------------------
template<bool PH2>
__device__ __forceinline__ void l3_phase(
    u16* As, u16* Ws,
    const u16* __restrict__ Ag, const u16* __restrict__ Wg, int j0,
    f32x4 acc[3][2][4], f32x4 accN[2][4])
{
  const int tid = threadIdx.x, wave = tid >> 6, lane = tid & 63;
  const int wmh = wave >> 1, wj = wave & 1;
  const int lrow = lane & 15, lq = lane >> 4;
  const int arow = wave * 8 + (lane >> 3);
  const int acol = (lane & 7) * 8;

  for (int k0 = 0; k0 < H_; k0 += 64) {
    __syncthreads();
    #pragma unroll
    for (int rd = 0; rd < 4; rd++)
      gl2lds16(Ag + (size_t)(rd * 32 + arow) * H_ + (k0 + acol), As + rd * 2048 + wave * 512);
    #pragma unroll
    for (int rd = 0; rd < 6; rd++)
      gl2lds16(Wg + (size_t)((rd >> 1) * 1024 + j0 + (rd & 1) * 32 + arow) * H_ + (k0 + acol),
               Ws + rd * 2048 + wave * 512);
    __syncthreads();
    #pragma unroll
    for (int kk = 0; kk < 64; kk += 32) {
      bf16x8 af[4];
      #pragma unroll
      for (int i = 0; i < 4; i++)
        af[i] = *(const bf16x8*)&As[(wmh * 64 + i * 16 + lrow) * 64 + kk + lq * 8];
      #pragma unroll
      for (int g = 0; g < 3; g++) {
        #pragma unroll
        for (int u = 0; u < 2; u++) {
          bf16x8 bw = *(const bf16x8*)&Ws[(g * 64 + wj * 32 + u * 16 + lrow) * 64 + kk + lq * 8];
          #pragma unroll
          for (int i = 0; i < 4; i++) {
            if (PH2 && g == 2)
              accN[u][i] = __builtin_amdgcn_mfma_f32_16x16x32_bf16(af[i], bw, accN[u][i], 0, 0, 0);
            else
              acc[g][u][i] = __builtin_amdgcn_mfma_f32_16x16x32_bf16(af[i], bw, acc[g][u][i], 0, 0, 0);
          }
        }
      }
    }
  }
}

// ---------------------------------------------------------------------------
// gates0_fused: gh0 = h1old @ whh0^T (3 gates, fp32 acc) with GRU-cell0 fused
// into the epilogue: gi0 = Egi[c[b]] (has b_ih0) + Gz; h1new = GRU(gi0, gh0).
// gh0 never touches memory. 512 blocks of 128b x 64j. h1 ping-pong (in-place
// would race with other blocks' K-loop reads of h1old).
// ---------------------------------------------------------------------------
__global__ __launch_bounds__(256, 2) void gates0_fused(
    const u16* __restrict__ h1old, const u16* __restrict__ whh0,
    const float* __restrict__ b_hh0,
    const int* __restrict__ c, const u16* __restrict__ Egi,
    const u16* __restrict__ Gz, u16* __restrict__ h1new)
{
  __shared__ __align__(16) u16 As[128 * 64];
  __shared__ __align__(16) u16 Ws[192 * 64];
  const int bid = blockIdx.x;
  const int xcd = bid & 7, k = bid >> 3;   // k: 0..63
  const int jt = xcd * 2 + (k & 1);        // 0..15
  const int m  = k >> 1;                   // 0..31
  const int m0 = m * 128, j0 = jt * 64;

  f32x4 acc[3][2][4] = {};
  f32x4 accN[2][4];                        // unused (PH2=false)

  l3_phase<false>(As, Ws, h1old + (size_t)m0 * H_, whh0, j0, acc, accN);

  const int tid = threadIdx.x, wave = tid >> 6, lane = tid & 63;
  const int wmh = wave >> 1, wj = wave & 1;
  const int lrow = lane & 15, lq = lane >> 4;

  #pragma unroll
  for (int i = 0; i < 4; i++) {
    #pragma unroll
    for (int rr = 0; rr < 4; rr++) {
      const int row = m0 + wmh * 64 + i * 16 + lq * 4 + rr;
      const int cv = c[row];
      const u16* eg = Egi + (size_t)cv * H3_;
      const u16* gz = Gz + (size_t)row * H3_;
      #pragma unroll
      for (int u = 0; u < 2; u++) {
        const int j = j0 + wj * 32 + u * 16 + lrow;
        float gir = bf2f(eg[j])          + bf2f(gz[j]);
        float giz = bf2f(eg[H_ + j])     + bf2f(gz[H_ + j]);
        float gin = bf2f(eg[2 * H_ + j]) + bf2f(gz[2 * H_ + j]);
        float ghr = acc[0][u][i][rr] + b_hh0[j];
        float ghz = acc[1][u][i][rr] + b_hh0[H_ + j];
        float ghn = acc[2][u][i][rr] + b_hh0[2 * H_ + j];
        float r  = sigm(gir + ghr);
        float zg = sigm(giz + ghz);
        float nn = tanh_fast(gin + r * ghn);
        float hold = bf2f(h1old[(size_t)row * H_ + j]);
        h1new[(size_t)row * H_ + j] = f2bf((1.f - zg) * nn + zg * hold);
      }
    }
  }
}

// ---------------------------------------------------------------------------
// gemm_l3: fused layer-1 GRU (dual GEMM, cell1 epilogue). h2 ping-pong.
// ---------------------------------------------------------------------------
__global__ __launch_bounds__(256, 2) void gemm_l3(
    const u16* __restrict__ h1, const u16* __restrict__ h2old,
    const u16* __restrict__ wih1, const u16* __restrict__ whh1,
    const float* __restrict__ b_ih1, const float* __restrict__ b_hh1,
    u16* __restrict__ h2new)
{
  __shared__ __align__(16) u16 As[128 * 64];
  __shared__ __align__(16) u16 Ws[192 * 64];
  const int bid = blockIdx.x;
  const int xcd = bid & 7, k = bid >> 3;   // k: 0..63
  const int jt = xcd * 2 + (k & 1);        // 0..15
  const int m  = k >> 1;                   // 0..31
  const int m0 = m * 128, j0 = jt * 64;

  f32x4 acc[3][2][4] = {};
  f32x4 accN[2][4] = {};

  l3_phase<false>(As, Ws, h1    + (size_t)m0 * H_, wih1, j0, acc, accN);
  l3_phase<true >(As, Ws, h2old + (size_t)m0 * H_, whh1, j0, acc, accN);

  const int tid = threadIdx.x, wave = tid >> 6, lane = tid & 63;
  const int wmh = wave >> 1, wj = wave & 1;
  const int lrow = lane & 15, lq = lane >> 4;

  #pragma unroll
  for (int u = 0; u < 2; u++) {
    const int j = j0 + wj * 32 + u * 16 + lrow;
    const float bR  = b_ih1[j] + b_hh1[j];
    const float bZ  = b_ih1[H_ + j] + b_hh1[H_ + j];
    const float bNi = b_ih1[2 * H_ + j];
    const float bNh = b_hh1[2 * H_ + j];
    #pragma unroll
    for (int i = 0; i < 4; i++) {
      #pragma unroll
      for (int rr = 0; rr < 4; rr++) {
        const int row = m0 + wmh * 64 + i * 16 + lq * 4 + rr;
        float r  = sigm(acc[0][u][i][rr] + bR);
        float zg = sigm(acc[1][u][i][rr] + bZ);
        float nn = tanh_fast(acc[2][u][i][rr] + bNi + r * (accN[u][i][rr] + bNh));
        float hold = bf2f(h2old[(size_t)row * H_ + j]);
        h2new[(size_t)row * H_ + j] = f2bf((1.f - zg) * nn + zg * hold);
      }
    }
  }
}

// ---------------------------------------------------------------------------
// out = h2 @ Wo^T + Oz; writes d_out[:,t,:], per-row argmax -> cnew.
// ---------------------------------------------------------------------------
__global__ __launch_bounds__(256) void out_only(
    const u16* __restrict__ h2, const u16* __restrict__ Wo,
    const float* __restrict__ Oz, float* __restrict__ outp,
    int* __restrict__ cnew, int t)
{
  __shared__ __align__(16) u16 As[64 * 64];
  __shared__ __align__(16) u16 Ws[128 * 64];
  const int tid = threadIdx.x, wave = tid >> 6, lane = tid & 63;
  const int b0 = blockIdx.x * 64;
  const int lrow = lane & 15, lq = lane >> 4;
  const int arow = wave * 8 + (lane >> 3);
  const int acol = (lane & 7) * 8;
  f32x4 acc[8] = {};

  for (int k0 = 0; k0 < H_; k0 += 64) {
    __syncthreads();
    #pragma unroll
    for (int rd = 0; rd < 2; rd++)
      gl2lds16(h2 + (size_t)(b0 + rd * 32 + arow) * H_ + k0 + acol, As + rd * 2048 + wave * 512);
    #pragma unroll
    for (int rd = 0; rd < 4; rd++)
      gl2lds16(Wo + (size_t)(rd * 32 + arow) * H_ + k0 + acol, Ws + rd * 2048 + wave * 512);
    __syncthreads();
    #pragma unroll
    for (int kk = 0; kk < 64; kk += 32) {
      bf16x8 af = *(const bf16x8*)&As[(wave * 16 + lrow) * 64 + kk + lq * 8];
      #pragma unroll
      for (int j = 0; j < 8; j++) {
        bf16x8 bw = *(const bf16x8*)&Ws[(j * 16 + lrow) * 64 + kk + lq * 8];
        acc[j] = __builtin_amdgcn_mfma_f32_16x16x32_bf16(af, bw, acc[j], 0, 0, 0);
      }
    }
  }

  #pragma unroll
  for (int r = 0; r < 4; r++) {
    const int row = b0 + wave * 16 + lq * 4 + r;
    float mv = -3.4e38f; int mi = 0;
    #pragma unroll
    for (int j = 0; j < 8; j++) {
      const int col = j * 16 + lrow;
      float v = acc[j][r] + Oz[(size_t)row * C_ + col];
      outp[(size_t)row * (T_ * C_) + t * C_ + col] = v;
      if (v > mv) { mv = v; mi = col; }
    }
    #pragma unroll
    for (int off = 1; off < 16; off <<= 1) {
      float ov = __shfl_xor(mv, off);
      int   oi = __shfl_xor(mi, off);
      if (ov > mv || (ov == mv && oi < mi)) { mv = ov; mi = oi; }
    }
    if (lrow == 0) cnew[row] = mi;
  }
}

// --------------------------- conversion kernels ----------------------------
__global__ __launch_bounds__(256) void conv_bf16_k(const float* __restrict__ s, u16* __restrict__ d, int n) {
  int i = blockIdx.x * 256 + threadIdx.x;
  if (i < n) d[i] = f2bf(s[i]);
}
__global__ __launch_bounds__(256) void conv_split_k(const float* __restrict__ s, u16* __restrict__ dA,
                                                    u16* __restrict__ dZ, int rows) {
  int i = blockIdx.x * 256 + threadIdx.x;
  if (i >= rows * 1280) return;
  int rr = i / 1280, col = i - rr * 1280;
  float v = s[i];
  if (col < 1024) dA[(size_t)rr * 1024 + col] = f2bf(v);
  else            dZ[(size_t)rr * 256 + (col - 1024)] = f2bf(v);
}
__global__ __launch_bounds__(256) void conv_swish_k(const float* __restrict__ s, u16* __restrict__ d, int n) {
  int i = blockIdx.x * 256 + threadIdx.x;
  if (i < n) { float e = s[i]; d[i] = f2bf(e * sigm(e)); }
}

// ---------------------------------------------------------------------------
static inline char* wsal(char*& p, size_t bytes) {
  char* r = p; p += (bytes + 255) & ~(size_t)255; return r;
}

extern "C" void kernel_launch(void* const* d_in, const int* in_sizes, int n_in,
                              void* d_out, int out_size, void* d_ws, size_t ws_size,
                              hipStream_t stream) {
  const float* z       = (const float*)d_in[0];
  const float* embed_w = (const float*)d_in[1];
  const float* z2h_w   = (const float*)d_in[2];
  const float* z2h_b   = (const float*)d_in[3];
  const float* w_ih0   = (const float*)d_in[4];
  const float* w_hh0   = (const float*)d_in[5];
  const float* b_ih0   = (const float*)d_in[6];
  const float* b_hh0   = (const float*)d_in[7];
  const float* w_ih1   = (const float*)d_in[8];
  const float* w_hh1   = (const float*)d_in[9];
  const float* b_ih1   = (const float*)d_in[10];
  const float* b_hh1   = (const float*)d_in[11];
  const float* h2o_w   = (const float*)d_in[12];
  const float* h2o_b   = (const float*)d_in[13];
  float* outp = (float*)d_out;

  char* p = (char*)d_ws;
  u16* whh0  = (u16*)wsal(p, (size_t)H3_ * H_ * 2);
  u16* wih1  = (u16*)wsal(p, (size_t)H3_ * H_ * 2);
  u16* whh1  = (u16*)wsal(p, (size_t)H3_ * H_ * 2);
  u16* wih0a = (u16*)wsal(p, (size_t)H3_ * H_ * 2);
  u16* wih0z = (u16*)wsal(p, (size_t)H3_ * L_ * 2);
  u16* h2oa  = (u16*)wsal(p, (size_t)C_ * H_ * 2);
  u16* h2oz  = (u16*)wsal(p, (size_t)C_ * L_ * 2);
  u16* z2hb  = (u16*)wsal(p, (size_t)H_ * L_ * 2);
  u16* zb    = (u16*)wsal(p, (size_t)B_ * L_ * 2);
  u16* swe   = (u16*)wsal(p, (size_t)C_ * H_ * 2);
  u16* EgiB  = (u16*)wsal(p, (size_t)C_ * H3_ * 2);
  u16* Gz    = (u16*)wsal(p, (size_t)B_ * H3_ * 2);
  float* Oz  = (float*)wsal(p, (size_t)B_ * C_ * 4);
  u16* h1a   = (u16*)wsal(p, (size_t)B_ * H_ * 2);
  u16* h1b   = (u16*)wsal(p, (size_t)B_ * H_ * 2);
  u16* h2a   = (u16*)wsal(p, (size_t)B_ * H_ * 2);
  u16* h2b   = (u16*)wsal(p, (size_t)B_ * H_ * 2);
  int* cbuf  = (int*)wsal(p, (size_t)B_ * 4);

  // ---- one-time (per call) precompute ----
  conv_bf16_k<<<(B_*L_ + 255)/256, 256, 0, stream>>>(z, zb, B_*L_);
  conv_bf16_k<<<(H_*L_ + 255)/256, 256, 0, stream>>>(z2h_w, z2hb, H_*L_);
  conv_bf16_k<<<(H3_*H_ + 255)/256, 256, 0, stream>>>(w_hh0, whh0, H3_*H_);
  conv_bf16_k<<<(H3_*H_ + 255)/256, 256, 0, stream>>>(w_ih1, wih1, H3_*H_);
  conv_bf16_k<<<(H3_*H_ + 255)/256, 256, 0, stream>>>(w_hh1, whh1, H3_*H_);
  conv_split_k<<<(H3_*1280 + 255)/256, 256, 0, stream>>>(w_ih0, wih0a, wih0z, H3_);
  conv_split_k<<<(C_*1280 + 255)/256, 256, 0, stream>>>(h2o_w, h2oa, h2oz, C_);
  conv_swish_k<<<(C_*H_ + 255)/256, 256, 0, stream>>>(embed_w, swe, C_*H_);
  hipMemsetAsync(cbuf, 0, B_ * sizeof(int), stream);        // c0 = SOS = 0

  // h0 = z @ z2h_w^T + b  -> h1a and h2a
  gemm_bt<2><<<dim3(H_/128, B_/128), 256, 0, stream>>>(zb, L_, z2hb, L_, z2h_b, h1a, h2a, H_, L_);
  // E_gi[c] = swish(embed)[c] @ w_ih0[:, :H]^T + b_ih0   (bf16)
  gemm_bt<1><<<dim3(H3_/128, 1), 256, 0, stream>>>(swe, H_, wih0a, H_, b_ih0, EgiB, nullptr, H3_, H_);
  // Gz = z @ w_ih0[:, H:]^T  (loop-invariant)
  gemm_bt<1><<<dim3(H3_/128, B_/128), 256, 0, stream>>>(zb, L_, wih0z, L_, nullptr, Gz, nullptr, H3_, L_);
  // Oz = z @ h2o_w[:, H:]^T + h2o_b  (loop-invariant)
  gemm_bt<0><<<dim3(1, B_/128), 256, 0, stream>>>(zb, L_, h2oz, L_, h2o_b, Oz, nullptr, C_, L_);

  // ---- 64 sequential decode steps: 3 dispatches each ----
  u16 *h1c = h1a, *h1n = h1b, *h2c = h2a, *h2n = h2b;
  for (int t = 0; t < T_; t++) {
    // h1n <- GRUcell0(Egi[c], Gz, h1c @ whh0^T, h1c)   (fused GEMM+cell)
    gates0_fused<<<512, 256, 0, stream>>>(h1c, whh0, b_hh0, cbuf, EgiB, Gz, h1n);
    // h2n <- GRUcell1(h1n @ wih1^T, h2c @ whh1^T, h2c) (fused dual GEMM+cell)
    gemm_l3<<<512, 256, 0, stream>>>(h1n, h2c, wih1, whh1, b_ih1, b_hh1, h2n);
    // logits(t) from h2n; writes d_out[:,t,:], argmax -> cbuf (for step t+1)
    out_only<<<64, 256, 0, stream>>>(h2n, h2oa, Oz, outp, cbuf, t);
    u16* tmp;
    tmp = h1c; h1c = h1n; h1n = tmp;
    tmp = h2c; h2c = h2n; h2n = tmp;
  }
}